// Round 1
// baseline (529.606 us; speedup 1.0000x reference)
//
#include <hip/hip_runtime.h>

// ---------------------------------------------------------------------------
// Stage sizes
//   x:      [32, 3, 128, 128]
//   y (ws): [32, 32, 64, 64]    = 4,194,304 floats  (conv+relu+pool out)
//   g (ws): [32, 4096, 64]      = 8,388,608 floats  (GCN out = "flat")
//   f1(ws): [32, 128]           = 4,096 floats      (fc1 split-K accumulator)
//   out:    [32, 101]
// ---------------------------------------------------------------------------

// ========================= Kernel 1: conv+relu+pool =========================
// grid 512 = 32 batches * 16 tiles (16x16 pooled tile), block 256
__global__ __launch_bounds__(256) void k_conv_pool(
    const float* __restrict__ x, const float* __restrict__ cw,
    const float* __restrict__ cb, float* __restrict__ y)
{
    __shared__ float wl[864];            // 32*3*3*3 weights
    __shared__ float tin[3 * 34 * 36];   // 34x34 input patch per channel, row pad->36

    int blk = blockIdx.x;
    int b = blk >> 4;
    int tile = blk & 15;
    int ph0 = (tile >> 2) << 4;
    int pw0 = (tile & 3) << 4;
    int t = threadIdx.x;

    for (int i = t; i < 864; i += 256) wl[i] = cw[i];

    int r0 = ph0 * 2 - 1;
    int c0 = pw0 * 2 - 1;
    for (int i = t; i < 3 * 34 * 34; i += 256) {
        int ci = i / 1156;
        int rem = i - ci * 1156;
        int yy = rem / 34;
        int xx = rem - yy * 34;
        int gr = r0 + yy, gc = c0 + xx;
        float v = 0.f;
        if (gr >= 0 && gr < 128 && gc >= 0 && gc < 128)
            v = x[((b * 3 + ci) * 128 + gr) * 128 + gc];
        tin[ci * 1224 + yy * 36 + xx] = v;
    }
    __syncthreads();

    int ph = t >> 4, pw = t & 15;
    float p[3][4][4];
#pragma unroll
    for (int ci = 0; ci < 3; ++ci)
#pragma unroll
        for (int dy = 0; dy < 4; ++dy) {
            const float2* row = (const float2*)&tin[ci * 1224 + (2 * ph + dy) * 36 + 2 * pw];
            float2 v0 = row[0], v1 = row[1];
            p[ci][dy][0] = v0.x; p[ci][dy][1] = v0.y;
            p[ci][dy][2] = v1.x; p[ci][dy][3] = v1.y;
        }

    int obase = (b * 32 * 64 + (ph0 + ph)) * 64 + pw0 + pw;
    for (int co = 0; co < 32; ++co) {
        float s00 = 0.f, s01 = 0.f, s10 = 0.f, s11 = 0.f;
#pragma unroll
        for (int ci = 0; ci < 3; ++ci)
#pragma unroll
            for (int ky = 0; ky < 3; ++ky)
#pragma unroll
                for (int kx = 0; kx < 3; ++kx) {
                    float wv = wl[co * 27 + ci * 9 + ky * 3 + kx];
                    s00 = fmaf(p[ci][ky][kx],         wv, s00);
                    s01 = fmaf(p[ci][ky][kx + 1],     wv, s01);
                    s10 = fmaf(p[ci][ky + 1][kx],     wv, s10);
                    s11 = fmaf(p[ci][ky + 1][kx + 1], wv, s11);
                }
        float m = fmaxf(fmaxf(s00, s01), fmaxf(s10, s11)) + cb[co];
        y[obase + co * 4096] = fmaxf(m, 0.f);
    }
}

// ============================ Kernel 2: GCN =================================
// Rewrite: relu( A_norm(X) @ W + b )  -- aggregate 32-dim raw feats first.
// Node n's raw features = y_flat[b, n*32 .. n*32+32) (the reshape is raw).
// grid 1024 = 32 batches * 32 row-pairs (128 nodes each), block 256
__device__ __forceinline__ float dinvf(int h, int w) {
    int d = 1 + (w > 0) + (w < 63) + (h > 0) + (h < 63);
    return rsqrtf((float)d);
}

__device__ __forceinline__ void acc4(const float* __restrict__ yb, int hq, int wq,
                                     int fh, float c,
                                     float4& a0, float4& a1, float4& a2, float4& a3)
{
    const float4* s = (const float4*)(yb + (((hq << 6) + wq) << 5) + fh);
    float4 v0 = s[0], v1 = s[1], v2 = s[2], v3 = s[3];
    a0.x = fmaf(c, v0.x, a0.x); a0.y = fmaf(c, v0.y, a0.y);
    a0.z = fmaf(c, v0.z, a0.z); a0.w = fmaf(c, v0.w, a0.w);
    a1.x = fmaf(c, v1.x, a1.x); a1.y = fmaf(c, v1.y, a1.y);
    a1.z = fmaf(c, v1.z, a1.z); a1.w = fmaf(c, v1.w, a1.w);
    a2.x = fmaf(c, v2.x, a2.x); a2.y = fmaf(c, v2.y, a2.y);
    a2.z = fmaf(c, v2.z, a2.z); a2.w = fmaf(c, v2.w, a2.w);
    a3.x = fmaf(c, v3.x, a3.x); a3.y = fmaf(c, v3.y, a3.y);
    a3.z = fmaf(c, v3.z, a3.z); a3.w = fmaf(c, v3.w, a3.w);
}

__global__ __launch_bounds__(256) void k_gcn(
    const float* __restrict__ y, const float* __restrict__ gw,
    const float* __restrict__ gb, float* __restrict__ g)
{
    __shared__ float zl[128 * 36];   // aggregated 32-dim feats, row pad->36

    int blk = blockIdx.x;
    int b = blk >> 5;
    int r = blk & 31;                // grid rows 2r, 2r+1
    int t = threadIdx.x;
    const float* yb = y + b * 131072;

    int lane = t & 63;
    int wave = t >> 6;
    float wreg[32];                  // W column for this lane's output feature
#pragma unroll
    for (int f = 0; f < 32; ++f) wreg[f] = gw[f * 64 + lane];
    float bias = gb[lane];

    // ---- phase 1: z[l][0..31] = sum_q coeff * x_raw[q][0..31]
    {
        int l = t >> 1;
        int fh = (t & 1) << 4;
        int h = 2 * r + (l >> 6);
        int w = l & 63;
        float dp = dinvf(h, w);
        float4 a0 = {0,0,0,0}, a1 = {0,0,0,0}, a2 = {0,0,0,0}, a3 = {0,0,0,0};
        acc4(yb, h, w, fh, dp * dp, a0, a1, a2, a3);
        if (w > 0)  acc4(yb, h, w - 1, fh, dp * dinvf(h, w - 1), a0, a1, a2, a3);
        if (w < 63) acc4(yb, h, w + 1, fh, dp * dinvf(h, w + 1), a0, a1, a2, a3);
        if (h > 0)  acc4(yb, h - 1, w, fh, dp * dinvf(h - 1, w), a0, a1, a2, a3);
        if (h < 63) acc4(yb, h + 1, w, fh, dp * dinvf(h + 1, w), a0, a1, a2, a3);
        float4* zrow = (float4*)&zl[l * 36 + fh];
        zrow[0] = a0; zrow[1] = a1; zrow[2] = a2; zrow[3] = a3;
    }
    __syncthreads();

    // ---- phase 2: g[p][lane] = relu( z[p][:] . W[:,lane] + bias )
    int l0 = wave << 5;
    int pbase = r * 128;
    float* gout = g + (size_t)b * 262144;
    for (int n = 0; n < 32; ++n) {
        int l = l0 + n;
        const float4* zz = (const float4*)&zl[l * 36];
        float acc = bias;
#pragma unroll
        for (int f4 = 0; f4 < 8; ++f4) {
            float4 zv = zz[f4];
            acc = fmaf(zv.x, wreg[f4 * 4 + 0], acc);
            acc = fmaf(zv.y, wreg[f4 * 4 + 1], acc);
            acc = fmaf(zv.z, wreg[f4 * 4 + 2], acc);
            acc = fmaf(zv.w, wreg[f4 * 4 + 3], acc);
        }
        gout[(pbase + l) * 64 + lane] = fmaxf(acc, 0.f);
    }
}

// ============================ Kernel 3: fc1 =================================
// f1[32,128] += flat[32, kslab] @ w1[kslab, 128]^T  (split-K, atomics)
// grid 1024 (k-slab = 256 each), block 128
__global__ __launch_bounds__(128) void k_fc1(
    const float* __restrict__ flat, const float* __restrict__ w,
    float* __restrict__ f1)
{
    __shared__ float Al[32 * 36];    // [k][b], pad 36
    __shared__ float Bl[32 * 132];   // [k][j], pad 132

    int t = threadIdx.x;
    int k0 = blockIdx.x << 8;

    int bg = t >> 4;                 // 0..7
    int b0 = bg << 2;
    int jg = t & 15;                 // 0..15
    int j0 = jg << 3;
    float acc[4][8];
#pragma unroll
    for (int i = 0; i < 4; ++i)
#pragma unroll
        for (int jj = 0; jj < 8; ++jj) acc[i][jj] = 0.f;

    int ab = t >> 2;                 // A-staging row b (0..31)
    int akq = t & 3;

    for (int s = 0; s < 8; ++s) {
        int ks = k0 + (s << 5);
        // stage A (flat -> [k][b] transpose)
        {
            const float4* src = (const float4*)(flat + (size_t)ab * 262144 + ks + (akq << 3));
            float4 v0 = src[0], v1 = src[1];
            int kb = akq << 3;
            Al[(kb + 0) * 36 + ab] = v0.x;
            Al[(kb + 1) * 36 + ab] = v0.y;
            Al[(kb + 2) * 36 + ab] = v0.z;
            Al[(kb + 3) * 36 + ab] = v0.w;
            Al[(kb + 4) * 36 + ab] = v1.x;
            Al[(kb + 5) * 36 + ab] = v1.y;
            Al[(kb + 6) * 36 + ab] = v1.z;
            Al[(kb + 7) * 36 + ab] = v1.w;
        }
        // stage B (w1 row j=t -> [k][j] transpose); 128B contiguous per thread
        {
            const float4* src = (const float4*)(w + (size_t)t * 262144 + ks);
#pragma unroll
            for (int q = 0; q < 8; ++q) {
                float4 v = src[q];
                Bl[(q * 4 + 0) * 132 + t] = v.x;
                Bl[(q * 4 + 1) * 132 + t] = v.y;
                Bl[(q * 4 + 2) * 132 + t] = v.z;
                Bl[(q * 4 + 3) * 132 + t] = v.w;
            }
        }
        __syncthreads();

#pragma unroll 8
        for (int k = 0; k < 32; ++k) {
            float4 av  = *(const float4*)&Al[k * 36 + b0];
            float4 bv0 = *(const float4*)&Bl[k * 132 + j0];
            float4 bv1 = *(const float4*)&Bl[k * 132 + j0 + 4];
            float as[4] = {av.x, av.y, av.z, av.w};
            float bs[8] = {bv0.x, bv0.y, bv0.z, bv0.w, bv1.x, bv1.y, bv1.z, bv1.w};
#pragma unroll
            for (int i = 0; i < 4; ++i)
#pragma unroll
                for (int jj = 0; jj < 8; ++jj)
                    acc[i][jj] = fmaf(as[i], bs[jj], acc[i][jj]);
        }
        __syncthreads();
    }

#pragma unroll
    for (int i = 0; i < 4; ++i)
#pragma unroll
        for (int jj = 0; jj < 8; ++jj)
            atomicAdd(&f1[(b0 + i) * 128 + j0 + jj], acc[i][jj]);
}

// ============================ Kernel 4: fc2 =================================
// out[b,c] = sum_j relu(f1[b,j] + b1[j]) * w2[c,j] + b2[c]
__global__ __launch_bounds__(256) void k_fc2(
    const float* __restrict__ f1, const float* __restrict__ b1,
    const float* __restrict__ w2, const float* __restrict__ b2,
    float* __restrict__ out)
{
    int idx = blockIdx.x * 256 + threadIdx.x;
    if (idx >= 32 * 101) return;
    int b = idx / 101;
    int c = idx - b * 101;
    const float4* fp = (const float4*)(f1 + b * 128);
    const float4* bp = (const float4*)b1;
    const float4* wp = (const float4*)(w2 + c * 128);
    float acc = b2[c];
#pragma unroll
    for (int q = 0; q < 32; ++q) {
        float4 f = fp[q], bb = bp[q], ww = wp[q];
        acc = fmaf(fmaxf(f.x + bb.x, 0.f), ww.x, acc);
        acc = fmaf(fmaxf(f.y + bb.y, 0.f), ww.y, acc);
        acc = fmaf(fmaxf(f.z + bb.z, 0.f), ww.z, acc);
        acc = fmaf(fmaxf(f.w + bb.w, 0.f), ww.w, acc);
    }
    out[idx] = acc;
}

// ================================ launch ====================================
extern "C" void kernel_launch(void* const* d_in, const int* in_sizes, int n_in,
                              void* d_out, int out_size, void* d_ws, size_t ws_size,
                              hipStream_t stream)
{
    const float* x  = (const float*)d_in[0];
    const float* cw = (const float*)d_in[1];
    const float* cb = (const float*)d_in[2];
    const float* gw = (const float*)d_in[3];
    const float* gb = (const float*)d_in[4];
    const float* w1 = (const float*)d_in[5];
    const float* b1 = (const float*)d_in[6];
    const float* w2 = (const float*)d_in[7];
    const float* b2 = (const float*)d_in[8];
    float* out = (float*)d_out;

    float* y  = (float*)d_ws;        // 4,194,304 floats
    float* g  = y + 4194304;         // 8,388,608 floats
    float* f1 = g + 8388608;         // 4,096 floats

    k_conv_pool<<<512, 256, 0, stream>>>(x, cw, cb, y);
    k_gcn<<<1024, 256, 0, stream>>>(y, gw, gb, g);
    hipMemsetAsync(f1, 0, 4096 * sizeof(float), stream);
    k_fc1<<<1024, 128, 0, stream>>>(g, w1, f1);
    k_fc2<<<13, 256, 0, stream>>>(f1, b1, w2, b2, out);
}

// Round 2
// 281.327 us; speedup vs baseline: 1.8825x; 1.8825x over previous
//
#include <hip/hip_runtime.h>

// ---------------------------------------------------------------------------
// Stage sizes (floats)
//   x:       [32, 3, 128, 128]
//   y  (ws): [32, 32, 64, 64]   = 4,194,304   (conv+relu+pool out)
//   g  (ws): [32, 4096, 64]     = 8,388,608   (GCN out = "flat")
//   part(ws):[1024, 4096]       = 4,194,304   (fc1 split-K partials)
//   f1 (ws): [32, 128]          = 4,096
//   out:     [32, 101]
// ---------------------------------------------------------------------------

#define K_FC 262144

// ========================= Kernel 1: conv+relu+pool =========================
__global__ __launch_bounds__(256) void k_conv_pool(
    const float* __restrict__ x, const float* __restrict__ cw,
    const float* __restrict__ cb, float* __restrict__ y)
{
    __shared__ float wl[864];            // 32*3*3*3 weights
    __shared__ float tin[3 * 34 * 36];   // 34x34 input patch per channel, row pad->36

    int blk = blockIdx.x;
    int b = blk >> 4;
    int tile = blk & 15;
    int ph0 = (tile >> 2) << 4;
    int pw0 = (tile & 3) << 4;
    int t = threadIdx.x;

    for (int i = t; i < 864; i += 256) wl[i] = cw[i];

    int r0 = ph0 * 2 - 1;
    int c0 = pw0 * 2 - 1;
    for (int i = t; i < 3 * 34 * 34; i += 256) {
        int ci = i / 1156;
        int rem = i - ci * 1156;
        int yy = rem / 34;
        int xx = rem - yy * 34;
        int gr = r0 + yy, gc = c0 + xx;
        float v = 0.f;
        if (gr >= 0 && gr < 128 && gc >= 0 && gc < 128)
            v = x[((b * 3 + ci) * 128 + gr) * 128 + gc];
        tin[ci * 1224 + yy * 36 + xx] = v;
    }
    __syncthreads();

    int ph = t >> 4, pw = t & 15;
    float p[3][4][4];
#pragma unroll
    for (int ci = 0; ci < 3; ++ci)
#pragma unroll
        for (int dy = 0; dy < 4; ++dy) {
            const float2* row = (const float2*)&tin[ci * 1224 + (2 * ph + dy) * 36 + 2 * pw];
            float2 v0 = row[0], v1 = row[1];
            p[ci][dy][0] = v0.x; p[ci][dy][1] = v0.y;
            p[ci][dy][2] = v1.x; p[ci][dy][3] = v1.y;
        }

    int obase = (b * 32 * 64 + (ph0 + ph)) * 64 + pw0 + pw;
    for (int co = 0; co < 32; ++co) {
        float s00 = 0.f, s01 = 0.f, s10 = 0.f, s11 = 0.f;
#pragma unroll
        for (int ci = 0; ci < 3; ++ci)
#pragma unroll
            for (int ky = 0; ky < 3; ++ky)
#pragma unroll
                for (int kx = 0; kx < 3; ++kx) {
                    float wv = wl[co * 27 + ci * 9 + ky * 3 + kx];
                    s00 = fmaf(p[ci][ky][kx],         wv, s00);
                    s01 = fmaf(p[ci][ky][kx + 1],     wv, s01);
                    s10 = fmaf(p[ci][ky + 1][kx],     wv, s10);
                    s11 = fmaf(p[ci][ky + 1][kx + 1], wv, s11);
                }
        float m = fmaxf(fmaxf(s00, s01), fmaxf(s10, s11)) + cb[co];
        y[obase + co * 4096] = fmaxf(m, 0.f);
    }
}

// ============================ Kernel 2: GCN =================================
__device__ __forceinline__ float dinvf(int h, int w) {
    int d = 1 + (w > 0) + (w < 63) + (h > 0) + (h < 63);
    return rsqrtf((float)d);
}

__device__ __forceinline__ void acc4(const float* __restrict__ yb, int hq, int wq,
                                     int fh, float c,
                                     float4& a0, float4& a1, float4& a2, float4& a3)
{
    const float4* s = (const float4*)(yb + (((hq << 6) + wq) << 5) + fh);
    float4 v0 = s[0], v1 = s[1], v2 = s[2], v3 = s[3];
    a0.x = fmaf(c, v0.x, a0.x); a0.y = fmaf(c, v0.y, a0.y);
    a0.z = fmaf(c, v0.z, a0.z); a0.w = fmaf(c, v0.w, a0.w);
    a1.x = fmaf(c, v1.x, a1.x); a1.y = fmaf(c, v1.y, a1.y);
    a1.z = fmaf(c, v1.z, a1.z); a1.w = fmaf(c, v1.w, a1.w);
    a2.x = fmaf(c, v2.x, a2.x); a2.y = fmaf(c, v2.y, a2.y);
    a2.z = fmaf(c, v2.z, a2.z); a2.w = fmaf(c, v2.w, a2.w);
    a3.x = fmaf(c, v3.x, a3.x); a3.y = fmaf(c, v3.y, a3.y);
    a3.z = fmaf(c, v3.z, a3.z); a3.w = fmaf(c, v3.w, a3.w);
}

__global__ __launch_bounds__(256) void k_gcn(
    const float* __restrict__ y, const float* __restrict__ gw,
    const float* __restrict__ gb, float* __restrict__ g)
{
    __shared__ float zl[128 * 36];

    int blk = blockIdx.x;
    int b = blk >> 5;
    int r = blk & 31;
    int t = threadIdx.x;
    const float* yb = y + b * 131072;

    int lane = t & 63;
    int wave = t >> 6;
    float wreg[32];
#pragma unroll
    for (int f = 0; f < 32; ++f) wreg[f] = gw[f * 64 + lane];
    float bias = gb[lane];

    {
        int l = t >> 1;
        int fh = (t & 1) << 4;
        int h = 2 * r + (l >> 6);
        int w = l & 63;
        float dp = dinvf(h, w);
        float4 a0 = {0,0,0,0}, a1 = {0,0,0,0}, a2 = {0,0,0,0}, a3 = {0,0,0,0};
        acc4(yb, h, w, fh, dp * dp, a0, a1, a2, a3);
        if (w > 0)  acc4(yb, h, w - 1, fh, dp * dinvf(h, w - 1), a0, a1, a2, a3);
        if (w < 63) acc4(yb, h, w + 1, fh, dp * dinvf(h, w + 1), a0, a1, a2, a3);
        if (h > 0)  acc4(yb, h - 1, w, fh, dp * dinvf(h - 1, w), a0, a1, a2, a3);
        if (h < 63) acc4(yb, h + 1, w, fh, dp * dinvf(h + 1, w), a0, a1, a2, a3);
        float4* zrow = (float4*)&zl[l * 36 + fh];
        zrow[0] = a0; zrow[1] = a1; zrow[2] = a2; zrow[3] = a3;
    }
    __syncthreads();

    int l0 = wave << 5;
    int pbase = r * 128;
    float* gout = g + (size_t)b * 262144;
    for (int n = 0; n < 32; ++n) {
        int l = l0 + n;
        const float4* zz = (const float4*)&zl[l * 36];
        float acc = bias;
#pragma unroll
        for (int f4 = 0; f4 < 8; ++f4) {
            float4 zv = zz[f4];
            acc = fmaf(zv.x, wreg[f4 * 4 + 0], acc);
            acc = fmaf(zv.y, wreg[f4 * 4 + 1], acc);
            acc = fmaf(zv.z, wreg[f4 * 4 + 2], acc);
            acc = fmaf(zv.w, wreg[f4 * 4 + 3], acc);
        }
        gout[(pbase + l) * 64 + lane] = fmaxf(acc, 0.f);
    }
}

// ============================ Kernel 3: fc1 =================================
// partial[blk][32][128] = flat[32, k-slab] @ w1[k-slab, 128]^T
// grid 1024 (k-slab 256 each, staged in 8 steps of 32), block 256.
// k-major LDS tiles, no transpose; thread tile 4b x 8j; k-split x2 in-block.
__global__ __launch_bounds__(256, 4) void k_fc1(
    const float* __restrict__ flat, const float* __restrict__ w,
    float* __restrict__ partial)
{
    __shared__ float Wl[128 * 36];   // [j][k], pitch 36
    __shared__ float Al[32 * 36];    // [b][k], pitch 36

    int t = threadIdx.x;
    int blk = blockIdx.x;
    int k0 = blk << 8;

    int sub = t >> 7;                // k-half within step
    int tt = t & 127;
    int bg = tt >> 4;                // 0..7
    int b0 = bg << 2;
    int jg = tt & 15;                // j = jg + 16*jj  (stride-16 for bank spread)

    float acc[4][8];
#pragma unroll
    for (int i = 0; i < 4; ++i)
#pragma unroll
        for (int jj = 0; jj < 8; ++jj) acc[i][jj] = 0.f;

    for (int s = 0; s < 8; ++s) {
        int ks = k0 + (s << 5);
        // stage W tile [128][32]: 1024 float4, coalesced 128B runs per row
#pragma unroll
        for (int it = 0; it < 4; ++it) {
            int i = t + (it << 8);
            int j = i >> 3, kq = i & 7;
            float4 v = *(const float4*)(w + (size_t)j * K_FC + ks + (kq << 2));
            *(float4*)&Wl[j * 36 + (kq << 2)] = v;
        }
        // stage A tile [32][32]: 256 float4
        {
            int b = t >> 3, kq = t & 7;
            float4 v = *(const float4*)(flat + (size_t)b * K_FC + ks + (kq << 2));
            *(float4*)&Al[b * 36 + (kq << 2)] = v;
        }
        __syncthreads();

#pragma unroll
        for (int c = 0; c < 4; ++c) {
            int kk = (sub << 4) + (c << 2);
            float4 av[4];
#pragma unroll
            for (int i = 0; i < 4; ++i)
                av[i] = *(const float4*)&Al[(b0 + i) * 36 + kk];
#pragma unroll
            for (int jj = 0; jj < 8; ++jj) {
                float4 wv = *(const float4*)&Wl[(jg + (jj << 4)) * 36 + kk];
#pragma unroll
                for (int i = 0; i < 4; ++i) {
                    acc[i][jj] = fmaf(av[i].x, wv.x, acc[i][jj]);
                    acc[i][jj] = fmaf(av[i].y, wv.y, acc[i][jj]);
                    acc[i][jj] = fmaf(av[i].z, wv.z, acc[i][jj]);
                    acc[i][jj] = fmaf(av[i].w, wv.w, acc[i][jj]);
                }
            }
        }
        __syncthreads();
    }

    // inter-half reduce through LDS (reuse Wl), then plain partial store
    if (sub == 1) {
#pragma unroll
        for (int i = 0; i < 4; ++i)
#pragma unroll
            for (int jj = 0; jj < 8; ++jj)
                Wl[((i << 3) + jj) * 128 + tt] = acc[i][jj];
    }
    __syncthreads();
    if (sub == 0) {
        float* pout = partial + ((size_t)blk << 12);
#pragma unroll
        for (int i = 0; i < 4; ++i)
#pragma unroll
            for (int jj = 0; jj < 8; ++jj)
                pout[(b0 + i) * 128 + jg + (jj << 4)] =
                    acc[i][jj] + Wl[((i << 3) + jj) * 128 + tt];
    }
}

// ==================== Kernel 3b: split-K partial reduce =====================
// f1[e] = sum_ns partial[ns][e];  grid 256, 4 float4-elements per block
__global__ __launch_bounds__(256) void k_red(
    const float* __restrict__ partial, float* __restrict__ f1)
{
    __shared__ float4 Sl[256];
    int t = threadIdx.x;
    int e4 = (blockIdx.x << 2) + (t & 3);
    int ng = t >> 2;
    const float4* p = (const float4*)partial;
    float4 a = {0.f, 0.f, 0.f, 0.f};
#pragma unroll
    for (int i = 0; i < 16; ++i) {
        int ns = ng + (i << 6);
        float4 v = p[(size_t)ns * 1024 + e4];
        a.x += v.x; a.y += v.y; a.z += v.z; a.w += v.w;
    }
    Sl[t] = a;
    __syncthreads();
    for (int off = 128; off >= 4; off >>= 1) {
        if (t < off) {
            float4 u = Sl[t], v = Sl[t + off];
            u.x += v.x; u.y += v.y; u.z += v.z; u.w += v.w;
            Sl[t] = u;
        }
        __syncthreads();
    }
    if (t < 4) ((float4*)f1)[(blockIdx.x << 2) + t] = Sl[t];
}

// ============================ Kernel 4: fc2 =================================
__global__ __launch_bounds__(256) void k_fc2(
    const float* __restrict__ f1, const float* __restrict__ b1,
    const float* __restrict__ w2, const float* __restrict__ b2,
    float* __restrict__ out)
{
    int idx = blockIdx.x * 256 + threadIdx.x;
    if (idx >= 32 * 101) return;
    int b = idx / 101;
    int c = idx - b * 101;
    const float4* fp = (const float4*)(f1 + b * 128);
    const float4* bp = (const float4*)b1;
    const float4* wp = (const float4*)(w2 + c * 128);
    float acc = b2[c];
#pragma unroll
    for (int q = 0; q < 32; ++q) {
        float4 f = fp[q], bb = bp[q], ww = wp[q];
        acc = fmaf(fmaxf(f.x + bb.x, 0.f), ww.x, acc);
        acc = fmaf(fmaxf(f.y + bb.y, 0.f), ww.y, acc);
        acc = fmaf(fmaxf(f.z + bb.z, 0.f), ww.z, acc);
        acc = fmaf(fmaxf(f.w + bb.w, 0.f), ww.w, acc);
    }
    out[idx] = acc;
}

// ================================ launch ====================================
extern "C" void kernel_launch(void* const* d_in, const int* in_sizes, int n_in,
                              void* d_out, int out_size, void* d_ws, size_t ws_size,
                              hipStream_t stream)
{
    const float* x  = (const float*)d_in[0];
    const float* cw = (const float*)d_in[1];
    const float* cb = (const float*)d_in[2];
    const float* gw = (const float*)d_in[3];
    const float* gb = (const float*)d_in[4];
    const float* w1 = (const float*)d_in[5];
    const float* b1 = (const float*)d_in[6];
    const float* w2 = (const float*)d_in[7];
    const float* b2 = (const float*)d_in[8];
    float* out = (float*)d_out;

    float* y       = (float*)d_ws;           // 4,194,304
    float* g       = y + 4194304;            // 8,388,608
    float* partial = g + 8388608;            // 4,194,304
    float* f1      = partial + 4194304;      // 4,096

    k_conv_pool<<<512, 256, 0, stream>>>(x, cw, cb, y);
    k_gcn<<<1024, 256, 0, stream>>>(y, gw, gb, g);
    k_fc1<<<1024, 256, 0, stream>>>(g, w1, partial);
    k_red<<<256, 256, 0, stream>>>(partial, f1);
    k_fc2<<<13, 256, 0, stream>>>(f1, b1, w2, b2, out);
}